// Round 4
// baseline (264.929 us; speedup 1.0000x reference)
//
#include <hip/hip_runtime.h>
#include <math.h>

#define NCLASS 1000
#define NCHUNK 250            // 1000 / 4 float4 chunks per row
#define RPW 4                 // rows per wave (processed sequentially)
#define WPB 4                 // waves per block
#define RPB (RPW * WPB)       // rows per block = 16
#define NGROUP 64             // level-1 counter groups (1 cacheline each)
#define CSTRIDE 16            // uints per counter line (64 B)

// Single fused kernel: per-block D-slice max + 16 rows of fused
// max/argmax + logsumexp + gather; last-done block folds the partials.
// Completion detection is HIERARCHICAL: 2048 same-address RMWs on one
// counter serialized at ~60ns each (~120us tail, rounds 2-3). Now each
// block RMWs its group line (32/line, 64 lines in parallel) and only
// group-last blocks touch the global line (64 RMWs).
__global__ __launch_bounds__(256) void hce_fused(
    const float* __restrict__ y_pred,
    const int*   __restrict__ y_true,
    const float* __restrict__ D,
    float* __restrict__ partial,          // [0,nb): sums; [nb,2nb): maxes
    unsigned int* __restrict__ gcnt,      // 64 lines + 1 global line, zeroed
    float* __restrict__ out,
    int nb, int dsize, float invB)
{
    const int tid  = threadIdx.x;
    const int lane = tid & 63;
    const int wave = tid >> 6;
    const int b    = blockIdx.x;

    // ---- distance_matrix max over this block's slice ----
    float dm = -1.0f;                     // D is uniform[0,1): nonnegative
    for (int i = b * 256 + tid; i < dsize; i += nb * 256)
        dm = fmaxf(dm, D[i]);

    const int nt = (lane < NCHUNK - 192) ? 4 : 3;   // lanes 0..57 own 4 chunks
    const int row0 = b * RPB + wave * RPW;

    float acc = 0.0f;
    for (int r = 0; r < RPW; ++r) {
        const int row = row0 + r;
        const float4* rp4 = (const float4*)(y_pred + (size_t)row * NCLASS);

        float4 v[4];
        #pragma unroll
        for (int t = 0; t < 4; ++t) {
            int c = lane + 64 * t;
            if (c < NCHUNK) v[t] = rp4[c];
        }

        // phase 1: max + argmax (first occurrence = min col among ties)
        float m = -INFINITY; int arg = 0;
        #pragma unroll
        for (int t = 0; t < 4; ++t) {
            if (t < nt) {
                int col = 4 * (lane + 64 * t);
                if (v[t].x > m) { m = v[t].x; arg = col;     }
                if (v[t].y > m) { m = v[t].y; arg = col + 1; }
                if (v[t].z > m) { m = v[t].z; arg = col + 2; }
                if (v[t].w > m) { m = v[t].w; arg = col + 3; }
            }
        }
        #pragma unroll
        for (int off = 32; off; off >>= 1) {
            float om = __shfl_xor(m,   off, 64);
            int   oa = __shfl_xor(arg, off, 64);
            if (om > m || (om == m && oa < arg)) { m = om; arg = oa; }
        }

        // phase 2: sum of exp(x - m)
        float s = 0.0f;
        #pragma unroll
        for (int t = 0; t < 4; ++t) {
            if (t < nt) {
                s += __expf(v[t].x - m) + __expf(v[t].y - m)
                   + __expf(v[t].z - m) + __expf(v[t].w - m);
            }
        }
        #pragma unroll
        for (int off = 32; off; off >>= 1)
            s += __shfl_xor(s, off, 64);

        if (lane == 0) {
            int   tgt = y_true[row];
            float xt  = y_pred[(size_t)row * NCLASS + tgt];
            acc += (xt - m - __logf(s)) * D[arg * NCLASS + tgt];
        }
    }

    // ---- block-level combine ----
    #pragma unroll
    for (int off = 32; off; off >>= 1)
        dm = fmaxf(dm, __shfl_xor(dm, off, 64));

    __shared__ float ssum[WPB], smax[WPB];
    __shared__ int lastflag;
    if (lane == 0) { ssum[wave] = acc; smax[wave] = dm; }
    __syncthreads();

    if (tid == 0) {
        float bs = ssum[0] + ssum[1] + ssum[2] + ssum[3];
        float bm = fmaxf(fmaxf(smax[0], smax[1]), fmaxf(smax[2], smax[3]));
        __hip_atomic_store(&partial[b],      bs, __ATOMIC_RELAXED, __HIP_MEMORY_SCOPE_AGENT);
        __hip_atomic_store(&partial[nb + b], bm, __ATOMIC_RELAXED, __HIP_MEMORY_SCOPE_AGENT);

        const int gsize = nb / NGROUP;            // blocks per group (32)
        const int g     = b / gsize;
        int last = 0;
        unsigned prev = __hip_atomic_fetch_add(&gcnt[g * CSTRIDE], 1u,
                            __ATOMIC_ACQ_REL, __HIP_MEMORY_SCOPE_AGENT);
        if (prev == (unsigned)(gsize - 1)) {      // group complete
            unsigned p2 = __hip_atomic_fetch_add(&gcnt[NGROUP * CSTRIDE], 1u,
                              __ATOMIC_ACQ_REL, __HIP_MEMORY_SCOPE_AGENT);
            last = (p2 == (unsigned)(NGROUP - 1));
        }
        lastflag = last;
    }
    __syncthreads();

    // ---- last-done block folds all partials ----
    if (lastflag) {
        float s = 0.0f, mx = -1.0f;
        for (int i = tid; i < nb; i += 256) {
            s  += __hip_atomic_load(&partial[i],      __ATOMIC_RELAXED, __HIP_MEMORY_SCOPE_AGENT);
            mx  = fmaxf(mx, __hip_atomic_load(&partial[nb + i],
                                              __ATOMIC_RELAXED, __HIP_MEMORY_SCOPE_AGENT));
        }
        #pragma unroll
        for (int off = 32; off; off >>= 1) {
            s  = s + __shfl_xor(s, off, 64);
            mx = fmaxf(mx, __shfl_xor(mx, off, 64));
        }
        if (lane == 0) { ssum[wave] = s; smax[wave] = mx; }
        __syncthreads();
        if (tid == 0) {
            float S = ssum[0] + ssum[1] + ssum[2] + ssum[3];
            float M = fmaxf(fmaxf(smax[0], smax[1]), fmaxf(smax[2], smax[3]));
            out[0] = -S * invB / M;
        }
    }
}

extern "C" void kernel_launch(void* const* d_in, const int* in_sizes, int n_in,
                              void* d_out, int out_size, void* d_ws, size_t ws_size,
                              hipStream_t stream) {
    const float* y_pred = (const float*)d_in[0];
    const int*   y_true = (const int*)  d_in[1];
    const float* D      = (const float*)d_in[2];
    // d_in[3] (fix_layer) is dead code in the reference.
    float* out = (float*)d_out;
    float* ws  = (float*)d_ws;

    const int B     = in_sizes[1];          // 32768
    const int dsize = in_sizes[2];          // 1000*1000
    const int nb    = B / RPB;              // 2048 blocks

    unsigned int* gcnt = (unsigned int*)(ws + 2 * (size_t)nb);
    hipMemsetAsync(gcnt, 0, (NGROUP + 1) * CSTRIDE * sizeof(unsigned int), stream);
    hce_fused<<<nb, 256, 0, stream>>>(y_pred, y_true, D, ws, gcnt, out,
                                      nb, dsize, 1.0f / (float)B);
}

// Round 5
// 199.235 us; speedup vs baseline: 1.3297x; 1.3297x over previous
//
#include <hip/hip_runtime.h>
#include <math.h>

#define NCLASS 1000
#define NCHUNK 250            // 1000 / 4 float4 chunks per row
#define RPW 2                 // rows per wave (interleaved, ILP 2)
#define WPB 4                 // waves per block
#define RPB (RPW * WPB)       // rows per block = 8

// Two-kernel, fence-free structure (R1) — the fused variants (R2-R4) all
// paid a ~50us tax from 2048 agent-scope acq_rel fences (L2 wb/inv storm).
// Inner loop: ONE 6-step online-softmax shuffle chain per row (max+argmax+
// sum fused) instead of two sequential chains; rows A/B interleaved for ILP;
// target gathers prefetched ahead of the reduction.
__global__ __launch_bounds__(256) void hce_main(
    const float* __restrict__ y_pred,
    const int*   __restrict__ y_true,
    const float* __restrict__ D,
    float* __restrict__ partial,   // [0,nb): sums; [nb,2nb): D-slice maxes
    int nb, int dsize)
{
    const int tid  = threadIdx.x;
    const int lane = tid & 63;
    const int wave = tid >> 6;
    const int b    = blockIdx.x;

    // ---- distance_matrix max over this block's slice (<=1 iter/thread) ----
    float dm = 0.0f;                      // D is uniform[0,1): nonnegative
    for (int i = b * 256 + tid; i < dsize; i += nb * 256)
        dm = fmaxf(dm, D[i]);

    const int row0 = b * RPB + wave * RPW;

    // ---- prefetch the serial gather chain for both rows ----
    const int tgtA = y_true[row0];
    const int tgtB = y_true[row0 + 1];
    const float* rowA = y_pred + (size_t)row0 * NCLASS;
    const float* rowB = rowA + NCLASS;
    const float xtA = rowA[tgtA];         // uniform addr -> broadcast load
    const float xtB = rowB[tgtB];

    // ---- load both rows (32 VGPRs payload; R2's 64 spilled) ----
    const float4* pA = (const float4*)rowA;
    const float4* pB = (const float4*)rowB;
    float4 vA[4], vB[4];
    #pragma unroll
    for (int t = 0; t < 4; ++t) {
        int c = lane + 64 * t;
        if (c < NCHUNK) { vA[t] = pA[c]; vB[t] = pB[c]; }
    }
    const int nt = (lane < NCHUNK - 192) ? 4 : 3;   // lanes 0..57 own 4 chunks

    // ---- local max/argmax (first-occurrence: cols ascend in scan order) ----
    float mA = -INFINITY, mB = -INFINITY;
    int   aA = 0,         aB = 0;
    #pragma unroll
    for (int t = 0; t < 4; ++t) {
        if (t < nt) {
            int col = 4 * (lane + 64 * t);
            const float fa[4] = { vA[t].x, vA[t].y, vA[t].z, vA[t].w };
            const float fb[4] = { vB[t].x, vB[t].y, vB[t].z, vB[t].w };
            #pragma unroll
            for (int j = 0; j < 4; ++j) {
                if (fa[j] > mA) { mA = fa[j]; aA = col + j; }
                if (fb[j] > mB) { mB = fb[j]; aB = col + j; }
            }
        }
    }

    // ---- local sum of exp(x - local_max) ----
    float sA = 0.0f, sB = 0.0f;
    #pragma unroll
    for (int t = 0; t < 4; ++t) {
        if (t < nt) {
            sA += __expf(vA[t].x - mA) + __expf(vA[t].y - mA)
                + __expf(vA[t].z - mA) + __expf(vA[t].w - mA);
            sB += __expf(vB[t].x - mB) + __expf(vB[t].y - mB)
                + __expf(vB[t].z - mB) + __expf(vB[t].w - mB);
        }
    }

    // ---- ONE 6-step online combine chain per row, A/B interleaved ----
    #pragma unroll
    for (int off = 32; off; off >>= 1) {
        float omA = __shfl_xor(mA, off, 64);
        int   oaA = __shfl_xor(aA, off, 64);
        float osA = __shfl_xor(sA, off, 64);
        float omB = __shfl_xor(mB, off, 64);
        int   oaB = __shfl_xor(aB, off, 64);
        float osB = __shfl_xor(sB, off, 64);

        float MA = fmaxf(mA, omA);
        sA = sA * __expf(mA - MA) + osA * __expf(omA - MA);
        aA = (omA > mA) ? oaA : ((omA == mA) ? min(aA, oaA) : aA);
        mA = MA;

        float MB = fmaxf(mB, omB);
        sB = sB * __expf(mB - MB) + osB * __expf(omB - MB);
        aB = (omB > mB) ? oaB : ((omB == mB) ? min(aB, oaB) : aB);
        mB = MB;
    }

    // ---- final gathers: lane 0 handles row A, lane 1 handles row B ----
    float contrib = 0.0f;
    if (lane == 0) contrib = (xtA - mA - __logf(sA)) * D[aA * NCLASS + tgtA];
    if (lane == 1) contrib = (xtB - mB - __logf(sB)) * D[aB * NCLASS + tgtB];
    contrib += __shfl_xor(contrib, 1, 64);          // lane 0 now has A+B

    // ---- block-level combine, plain stores (no fences) ----
    #pragma unroll
    for (int off = 32; off; off >>= 1)
        dm = fmaxf(dm, __shfl_xor(dm, off, 64));

    __shared__ float ssum[WPB], smax[WPB];
    if (lane == 0) { ssum[wave] = contrib; smax[wave] = dm; }
    __syncthreads();
    if (tid == 0) {
        partial[b]      = ssum[0] + ssum[1] + ssum[2] + ssum[3];
        partial[nb + b] = fmaxf(fmaxf(smax[0], smax[1]),
                                fmaxf(smax[2], smax[3]));
    }
}

__global__ __launch_bounds__(256) void hce_finalize(
    const float* __restrict__ partial, int nb,
    float* __restrict__ out, float invB)
{
    const int tid  = threadIdx.x;
    const int lane = tid & 63;
    const int wave = tid >> 6;
    float s = 0.0f, mx = 0.0f;
    for (int i = tid; i < nb; i += 256) {
        s  += partial[i];
        mx  = fmaxf(mx, partial[nb + i]);
    }
    #pragma unroll
    for (int off = 32; off; off >>= 1) {
        s  += __shfl_xor(s, off, 64);
        mx  = fmaxf(mx, __shfl_xor(mx, off, 64));
    }
    __shared__ float ss[4], sm[4];
    if (lane == 0) { ss[wave] = s; sm[wave] = mx; }
    __syncthreads();
    if (tid == 0) {
        float S = ss[0] + ss[1] + ss[2] + ss[3];
        float M = fmaxf(fmaxf(sm[0], sm[1]), fmaxf(sm[2], sm[3]));
        out[0] = -S * invB / M;
    }
}

extern "C" void kernel_launch(void* const* d_in, const int* in_sizes, int n_in,
                              void* d_out, int out_size, void* d_ws, size_t ws_size,
                              hipStream_t stream) {
    const float* y_pred = (const float*)d_in[0];
    const int*   y_true = (const int*)  d_in[1];
    const float* D      = (const float*)d_in[2];
    // d_in[3] (fix_layer) is dead code in the reference.
    float* out = (float*)d_out;
    float* ws  = (float*)d_ws;

    const int B     = in_sizes[1];          // 32768
    const int dsize = in_sizes[2];          // 1000*1000
    const int nb    = B / RPB;              // 4096 blocks

    hce_main<<<nb, 256, 0, stream>>>(y_pred, y_true, D, ws, nb, dsize);
    hce_finalize<<<1, 256, 0, stream>>>(ws, nb, out, 1.0f / (float)B);
}

// Round 6
// 198.772 us; speedup vs baseline: 1.3328x; 1.0023x over previous
//
#include <hip/hip_runtime.h>
#include <math.h>

#define NCLASS 1000
#define NCHUNK 250            // 1000 / 4 float4 chunks per row
#define RPW 4                 // rows per wave, all 4 preloaded (64 VGPR payload)
#define WPB 4                 // waves per block
#define RPB (RPW * WPB)       // rows per block = 16

// Two-kernel, fence-free structure (R1/R5) — in-kernel completion (R2-R4)
// pays ~50-70us in agent-scope acq_rel L2 wb/inv storms. This round: the
// R2 4-row preload idea, but with __launch_bounds__(256,4) so the VGPR cap
// is ~128 and the 64-VGPR payload does NOT spill (R2 spilled at a
// compiler-chosen 52-VGPR budget and ran 110us). 16 dwordx4 in flight per
// wave, one interleaved 6-step online-softmax butterfly for all 4 rows.
__global__ __launch_bounds__(256, 4) void hce_main(
    const float* __restrict__ y_pred,
    const int*   __restrict__ y_true,
    const float* __restrict__ D,
    float* __restrict__ partial,   // [0,nb): sums; [nb,2nb): D-slice maxes
    int nb, int dsize)
{
    const int tid  = threadIdx.x;
    const int lane = tid & 63;
    const int wave = tid >> 6;
    const int b    = blockIdx.x;

    const int row0 = b * RPB + wave * RPW;

    // ---- prefetch targets (one int4) and target logits (4 scalar loads) ----
    const int4 tgt4 = *(const int4*)(y_true + row0);   // row0 % 4 == 0
    const float* rp = y_pred + (size_t)row0 * NCLASS;
    const float xt0 = rp[tgt4.x];
    const float xt1 = rp[NCLASS + tgt4.y];
    const float xt2 = rp[2 * NCLASS + tgt4.z];
    const float xt3 = rp[3 * NCLASS + tgt4.w];

    // ---- preload all 4 rows: 16 dwordx4 in flight ----
    float4 v[RPW][4];
    #pragma unroll
    for (int r = 0; r < RPW; ++r) {
        const float4* p = (const float4*)(rp + (size_t)r * NCLASS);
        #pragma unroll
        for (int t = 0; t < 4; ++t) {
            int c = lane + 64 * t;
            if (c < NCHUNK) v[r][t] = p[c];
        }
    }

    // ---- distance_matrix max over this block's slice (overlaps loads) ----
    float dm = 0.0f;                      // D is uniform[0,1): nonnegative
    for (int i = b * 256 + tid; i < dsize; i += nb * 256)
        dm = fmaxf(dm, D[i]);

    const int nt = (lane < NCHUNK - 192) ? 4 : 3;   // lanes 0..57 own 4 chunks

    // ---- local max/argmax, 4 rows interleaved ----
    float m[RPW] = { -INFINITY, -INFINITY, -INFINITY, -INFINITY };
    int   a[RPW] = { 0, 0, 0, 0 };
    #pragma unroll
    for (int t = 0; t < 4; ++t) {
        if (t < nt) {
            int col = 4 * (lane + 64 * t);
            #pragma unroll
            for (int r = 0; r < RPW; ++r) {
                const float f[4] = { v[r][t].x, v[r][t].y, v[r][t].z, v[r][t].w };
                #pragma unroll
                for (int j = 0; j < 4; ++j)
                    if (f[j] > m[r]) { m[r] = f[j]; a[r] = col + j; }
            }
        }
    }

    // ---- local sum of exp(x - local_max), 4 rows interleaved ----
    float s[RPW] = { 0.0f, 0.0f, 0.0f, 0.0f };
    #pragma unroll
    for (int t = 0; t < 4; ++t) {
        if (t < nt) {
            #pragma unroll
            for (int r = 0; r < RPW; ++r) {
                s[r] += __expf(v[r][t].x - m[r]) + __expf(v[r][t].y - m[r])
                      + __expf(v[r][t].z - m[r]) + __expf(v[r][t].w - m[r]);
            }
        }
    }

    // ---- ONE 6-step online-softmax butterfly, 4-way ILP ----
    #pragma unroll
    for (int off = 32; off; off >>= 1) {
        #pragma unroll
        for (int r = 0; r < RPW; ++r) {
            float om = __shfl_xor(m[r], off, 64);
            int   oa = __shfl_xor(a[r], off, 64);
            float os = __shfl_xor(s[r], off, 64);
            float M  = fmaxf(m[r], om);
            s[r] = s[r] * __expf(m[r] - M) + os * __expf(om - M);
            a[r] = (om > m[r]) ? oa : ((om == m[r]) ? min(a[r], oa) : a[r]);
            m[r] = M;
        }
    }

    // ---- final gathers: lane r handles row r (r = 0..3) ----
    float contrib = 0.0f;
    if (lane == 0) contrib = (xt0 - m[0] - __logf(s[0])) * D[a[0] * NCLASS + tgt4.x];
    if (lane == 1) contrib = (xt1 - m[1] - __logf(s[1])) * D[a[1] * NCLASS + tgt4.y];
    if (lane == 2) contrib = (xt2 - m[2] - __logf(s[2])) * D[a[2] * NCLASS + tgt4.z];
    if (lane == 3) contrib = (xt3 - m[3] - __logf(s[3])) * D[a[3] * NCLASS + tgt4.w];
    contrib += __shfl_xor(contrib, 1, 64);
    contrib += __shfl_xor(contrib, 2, 64);          // lane 0: rows 0+1+2+3

    // ---- block-level combine, plain stores (no fences) ----
    #pragma unroll
    for (int off = 32; off; off >>= 1)
        dm = fmaxf(dm, __shfl_xor(dm, off, 64));

    __shared__ float ssum[WPB], smax[WPB];
    if (lane == 0) { ssum[wave] = contrib; smax[wave] = dm; }
    __syncthreads();
    if (tid == 0) {
        partial[b]      = ssum[0] + ssum[1] + ssum[2] + ssum[3];
        partial[nb + b] = fmaxf(fmaxf(smax[0], smax[1]),
                                fmaxf(smax[2], smax[3]));
    }
}

__global__ __launch_bounds__(256) void hce_finalize(
    const float* __restrict__ partial, int nb,
    float* __restrict__ out, float invB)
{
    const int tid  = threadIdx.x;
    const int lane = tid & 63;
    const int wave = tid >> 6;
    float s = 0.0f, mx = 0.0f;
    for (int i = tid; i < nb; i += 256) {
        s  += partial[i];
        mx  = fmaxf(mx, partial[nb + i]);
    }
    #pragma unroll
    for (int off = 32; off; off >>= 1) {
        s  += __shfl_xor(s, off, 64);
        mx  = fmaxf(mx, __shfl_xor(mx, off, 64));
    }
    __shared__ float ss[4], sm[4];
    if (lane == 0) { ss[wave] = s; sm[wave] = mx; }
    __syncthreads();
    if (tid == 0) {
        float S = ss[0] + ss[1] + ss[2] + ss[3];
        float M = fmaxf(fmaxf(sm[0], sm[1]), fmaxf(sm[2], sm[3]));
        out[0] = -S * invB / M;
    }
}

extern "C" void kernel_launch(void* const* d_in, const int* in_sizes, int n_in,
                              void* d_out, int out_size, void* d_ws, size_t ws_size,
                              hipStream_t stream) {
    const float* y_pred = (const float*)d_in[0];
    const int*   y_true = (const int*)  d_in[1];
    const float* D      = (const float*)d_in[2];
    // d_in[3] (fix_layer) is dead code in the reference.
    float* out = (float*)d_out;
    float* ws  = (float*)d_ws;

    const int B     = in_sizes[1];          // 32768
    const int dsize = in_sizes[2];          // 1000*1000
    const int nb    = B / RPB;              // 2048 blocks

    hce_main<<<nb, 256, 0, stream>>>(y_pred, y_true, D, ws, nb, dsize);
    hce_finalize<<<1, 256, 0, stream>>>(ws, nb, out, 1.0f / (float)B);
}